// Round 4
// baseline (1932.019 us; speedup 1.0000x reference)
//
#include <hip/hip_runtime.h>

#define HID 256
#define HH  64
#define WW  64

typedef _Float16 f16x8 __attribute__((ext_vector_type(8)));
typedef float    f32x4 __attribute__((ext_vector_type(4)));

// Raw barrier: waits only LDS ops (ds_write of hsum/hbel), leaves global
// stores in flight — __syncthreads() would drain vmcnt(0) every step (~250+cyc).
// sched_barrier(0) fences per skill rule #18 (compiler may hoist reg-only ops
// past inline-asm waitcnt).
#define LDS_BARRIER() do {                                   \
    asm volatile("s_waitcnt lgkmcnt(0)" ::: "memory");       \
    __builtin_amdgcn_sched_barrier(0);                       \
    __builtin_amdgcn_s_barrier();                            \
    __builtin_amdgcn_sched_barrier(0);                       \
  } while (0)

__global__ __launch_bounds__(256, 1)
void mrf_scan_kernel(const float* __restrict__ x,
                     const float* __restrict__ w_xh,
                     const float* __restrict__ b_xh,
                     const float* __restrict__ w_hh,
                     const float* __restrict__ b_hh,
                     float* __restrict__ out)
{
    const int n   = blockIdx.x;
    const int tid = threadIdx.x;
    const int wv  = tid >> 6;    // wave 0..3
    const int l   = tid & 63;
    const int l15 = l & 15;
    const int lq  = l >> 4;
    const int nbase = wv * 64;
    const int o   = nbase + l;   // this lane's output channel

    // hbel[w][o]: h of the row below, per column. Accessed ONLY as [.][o] per
    // lane (own channel) -> no cross-lane races, no conflicts.
    __shared__ __align__(16) _Float16 hbel[WW][HID];
    // hsum[cur][g] = h_prev[g] + h_below[w_next][g], ping-pong across steps.
    __shared__ __align__(16) _Float16 hsum[2][HID];
    // per-row x neighbor sums: xs4[w] = (s_c0, s_c1, s_c2, cnt)
    __shared__ __align__(16) float4   xs4[WW];

    // ---- zero-init LDS ----
    {
        unsigned int* z = (unsigned int*)(&hbel[0][0]);
        #pragma unroll
        for (int q = 0; q < (WW*HID/2)/256; ++q) z[tid + 256*q] = 0u;
        ((unsigned int*)(&hsum[0][0]))[tid] = 0u;   // covers both buffers
    }

    // ---- preload w_hh as MFMA B-fragments: B[k=g][col], col -> nbase+nt*16+l15 ----
    f16x8 Bf[4][8];
    #pragma unroll
    for (int nt = 0; nt < 4; ++nt) {
        const float* wr = w_hh + (size_t)(nbase + nt*16 + l15) * HID;
        #pragma unroll
        for (int kf = 0; kf < 8; ++kf) {
            const int g0 = kf*32 + lq*8;
            f16x8 b;
            #pragma unroll
            for (int j = 0; j < 8; ++j) b[j] = (_Float16)wr[g0 + j];
            Bf[nt][kf] = b;
        }
    }

    // per-lane channel constants
    const float wx0 = w_xh[o*3+0];
    const float wx1 = w_xh[o*3+1];
    const float wx2 = w_xh[o*3+2];
    const float bx  = b_xh[o];
    const float bh  = b_hh[o];

    const int    XP = HH*WW;
    const float* xn = x + (size_t)n * 3 * XP;
    float*     outn = out + (size_t)n * HID * XP;

    __syncthreads();   // init visible (cold path, full sync fine)

    int cur = 0;
    for (int k = 0; k < HH; ++k) {
        const int i    = HH - 1 - k;
        const int flip = ((i & 1) == 0);   // even rows scan right->left

        // ---- stage x neighbor sums for this row (waves 0..2; c = wave) ----
        if (tid < 192) {
            const int c = tid >> 6, w = tid & 63;
            const float* xc = xn + (size_t)c * XP;
            float s = 0.f;
            if (w > 0)    s += xc[i*WW + w - 1];
            if (w < WW-1) s += xc[i*WW + w + 1];
            if (i > 0)    s += xc[(i-1)*WW + w];
            if (i < HH-1) s += xc[(i+1)*WW + w];
            ((float*)&xs4[w])[c] = s;
            if (c == 0) {
                const float cnt = (float)((w>0) + (w<WW-1) + (i>0) + (i<HH-1));
                ((float*)&xs4[w])[3] = cnt;
            }
        }
        LDS_BARRIER();

        const float Fr = ((i != 0) ? 1.f : 0.f) + ((k != 0) ? 1.f : 0.f);
        float* outrow = outn + (size_t)i * WW;

        for (int t = 0; t < WW; ++t) {
            const int w  = flip ? (WW-1-t) : t;
            const int wn = (t < WW-1) ? (flip ? (WW-2-t) : (t+1)) : w;

            // ---- issue all LDS reads up front: A-frags, next-col below-h, xsums ----
            f16x8 Af[8];
            #pragma unroll
            for (int kf = 0; kf < 8; ++kf)
                Af[kf] = *(const f16x8*)((const char*)(&hsum[cur][0]) + kf*64 + lq*16);
            const _Float16 hb = hbel[wn][o];   // hoisted: latency hides under MFMAs
            const float4   xv = xs4[w];        // wave-uniform broadcast

            // per-lane x-logit (off the MFMA critical path)
            const float Ft = Fr + ((t != 0 && t != WW-1) ? 1.f : 0.f) + ((t != 0) ? 1.f : 0.f);
            float pre = xv.w * bx;
            pre = fmaf(xv.x, wx0, pre);
            pre = fmaf(xv.y, wx1, pre);
            pre = fmaf(xv.z, wx2, pre);
            pre = fmaf(Ft,   bh,  pre);

            // ---- 8 independent 4-deep MFMA chains (cuts dep latency vs 4x8) ----
            f32x4 cA[4], cB[4];
            #pragma unroll
            for (int nt = 0; nt < 4; ++nt) {
                cA[nt] = (f32x4){0.f,0.f,0.f,0.f};
                cB[nt] = (f32x4){0.f,0.f,0.f,0.f};
            }
            #pragma unroll
            for (int nt = 0; nt < 4; ++nt) {
                #pragma unroll
                for (int kf = 0; kf < 4; ++kf) {
                    cA[nt] = __builtin_amdgcn_mfma_f32_16x16x32_f16(Af[kf],   Bf[nt][kf],   cA[nt], 0, 0, 0);
                    cB[nt] = __builtin_amdgcn_mfma_f32_16x16x32_f16(Af[kf+4], Bf[nt][kf+4], cB[nt], 0, 0, 0);
                }
            }

            // all D rows equal (C=0, replicated A); lane picks its nt = lq, reg 0
            const float dA = (lq < 2) ? ((lq == 0) ? cA[0][0] : cA[1][0])
                                      : ((lq == 2) ? cA[2][0] : cA[3][0]);
            const float dB = (lq < 2) ? ((lq == 0) ? cB[0][0] : cB[1][0])
                                      : ((lq == 2) ? cB[2][0] : cB[3][0]);
            const float val = dA + dB + pre;
            const float e   = __expf(-val);
            const float s   = __builtin_amdgcn_rcpf(1.f + e);

            const _Float16 h16 = (_Float16)s;
            hbel[w][o] = h16;
            hsum[cur ^ 1][o] = (t < WW-1) ? (_Float16)(h16 + hb) : h16;

            outrow[(size_t)o * XP + w] = s;   // fire-and-forget; NOT drained by barrier

            LDS_BARRIER();
            cur ^= 1;
        }
    }
}

extern "C" void kernel_launch(void* const* d_in, const int* in_sizes, int n_in,
                              void* d_out, int out_size, void* d_ws, size_t ws_size,
                              hipStream_t stream) {
    const float* x    = (const float*)d_in[0];
    const float* w_xh = (const float*)d_in[1];
    const float* b_xh = (const float*)d_in[2];
    const float* w_hh = (const float*)d_in[3];
    const float* b_hh = (const float*)d_in[4];
    float* out = (float*)d_out;
    (void)in_sizes; (void)n_in; (void)d_ws; (void)ws_size; (void)out_size;

    mrf_scan_kernel<<<dim3(32), dim3(256), 0, stream>>>(x, w_xh, b_xh, w_hh, b_hh, out);
}